// Round 6
// baseline (2415.409 us; speedup 1.0000x reference)
//
#include <hip/hip_runtime.h>
#include <cstdint>
#include <cstddef>

#define DEV static __device__ __forceinline__

typedef unsigned short u16;
typedef unsigned int u32;
typedef __attribute__((ext_vector_type(8))) short short8;
typedef __attribute__((ext_vector_type(8))) __bf16 bf16x8;
typedef __attribute__((ext_vector_type(4))) float f32x4;

DEV u16 f2bf(float f) {
  u32 u = __builtin_bit_cast(u32, f);
  u32 r = (u + 0x7fffu + ((u >> 16) & 1u)) >> 16;
  return (u16)r;
}
DEV float bf2f(u16 h) { u32 u = ((u32)h) << 16; return __builtin_bit_cast(float, u); }
DEV u32 pack2(float a, float b) { return (u32)f2bf(a) | ((u32)f2bf(b) << 16); }

// ---------------- weight transpose + cast: src fp32 (K,N) -> dst bf16 (N,K) ----------------
__global__ __launch_bounds__(256) void k_tcast(const float* __restrict__ src, u16* __restrict__ dst,
                                               int K, int N, size_t sStride, size_t dStride) {
  __shared__ float tl[32][33];
  int tx = threadIdx.x, ty = threadIdx.y;
  int n0 = blockIdx.x * 32, k0 = blockIdx.y * 32;
  src += (size_t)blockIdx.z * sStride;
  dst += (size_t)blockIdx.z * dStride;
#pragma unroll
  for (int i = 0; i < 4; ++i)
    tl[ty + i * 8][tx] = src[(size_t)(k0 + ty + i * 8) * N + n0 + tx];
  __syncthreads();
#pragma unroll
  for (int i = 0; i < 4; ++i)
    dst[(size_t)(n0 + ty + i * 8) * K + k0 + tx] = f2bf(tl[tx][ty + i * 8]);
}

// ---------------- fp32 transpose with N-guard: src (K,N) -> dst (N,K); K % 32 == 0 ----------------
__global__ __launch_bounds__(256) void k_tcastf(const float* __restrict__ src, float* __restrict__ dst,
                                                int K, int N) {
  __shared__ float tl[32][33];
  int tx = threadIdx.x, ty = threadIdx.y;
  int n0 = blockIdx.x * 32, k0 = blockIdx.y * 32;
#pragma unroll
  for (int i = 0; i < 4; ++i)
    if (n0 + tx < N) tl[ty + i * 8][tx] = src[(size_t)(k0 + ty + i * 8) * N + n0 + tx];
  __syncthreads();
#pragma unroll
  for (int i = 0; i < 4; ++i)
    if (n0 + ty + i * 8 < N) dst[(size_t)(n0 + ty + i * 8) * K + k0 + tx] = tl[tx][ty + i * 8];
}

// ---------------- patch extraction: x (B,224,224,3) -> pA bf16 (6272, 768) ----------------
__global__ __launch_bounds__(256) void k_patch_extract(const float* __restrict__ x, u16* __restrict__ pA) {
  int idx = blockIdx.x * 256 + threadIdx.x;  // < 6272*768
  int token = idx / 768, kk = idx - token * 768;
  int b = token / 196, t = token - b * 196;
  int gy = t / 14, gx = t - gy * 14;
  int py = kk / 48, rem = kk - py * 48;
  int px = rem / 3, ch = rem - px * 3;
  size_t s = ((size_t)(b * 224 + gy * 16 + py) * 224 + (gx * 16 + px)) * 3 + ch;
  pA[idx] = f2bf(x[s]);
}

// ---------------- LayerNorm: h fp32 (6272,384) -> z bf16; wave/token, lane-contiguous ----------------
__global__ __launch_bounds__(256) void k_ln(const float* __restrict__ h, u16* __restrict__ z,
                                            const float* __restrict__ sc, const float* __restrict__ bi) {
  int wave = threadIdx.x >> 6, lane = threadIdx.x & 63;
  int token = blockIdx.x * 4 + wave;
  const float* hp = h + (size_t)token * 384 + lane * 6;
  float2 v0 = *(const float2*)hp;
  float2 v1 = *(const float2*)(hp + 2);
  float2 v2 = *(const float2*)(hp + 4);
  float sum = v0.x + v0.y + v1.x + v1.y + v2.x + v2.y;
  float sq = v0.x * v0.x + v0.y * v0.y + v1.x * v1.x + v1.y * v1.y + v2.x * v2.x + v2.y * v2.y;
#pragma unroll
  for (int o = 1; o < 64; o <<= 1) { sum += __shfl_xor(sum, o); sq += __shfl_xor(sq, o); }
  float mean = sum * (1.f / 384.f);
  float var = sq * (1.f / 384.f) - mean * mean;
  float rstd = rsqrtf(var + 1e-6f);
  const float* scp = sc + lane * 6;
  const float* bip = bi + lane * 6;
  float2 s0 = *(const float2*)scp, s1 = *(const float2*)(scp + 2), s2 = *(const float2*)(scp + 4);
  float2 b0 = *(const float2*)bip, b1 = *(const float2*)(bip + 2), b2 = *(const float2*)(bip + 4);
  u16* zp = z + (size_t)token * 384 + lane * 6;
  *(u32*)(zp)     = pack2((v0.x - mean) * rstd * s0.x + b0.x, (v0.y - mean) * rstd * s0.y + b0.y);
  *(u32*)(zp + 2) = pack2((v1.x - mean) * rstd * s1.x + b1.x, (v1.y - mean) * rstd * s1.y + b1.y);
  *(u32*)(zp + 4) = pack2((v2.x - mean) * rstd * s2.x + b2.x, (v2.y - mean) * rstd * s2.y + b2.y);
}

// ---------------- barrier-free per-wave GEMM: C = A(M,K) * BT(N,K), bf16 ----------------
// No LDS, no __syncthreads: each wave computes a (MI*16)x64 tile, loading MFMA fragments
// directly from global (16 rows x 64B lines per fragment; L1/L2 provide reuse).
// MODE 0: out0 fp32 = acc + bias0[n] + res[(m%196)*384+n]          (patch embed + pos)
// MODE 1: n<384 -> outb = bf16(acc+bias0[n]); else outb2 = bf16(sigmoid(acc+bias1[n-384]))
// MODE 2: outb bf16 = gelu_tanh(acc + bias0[n]), row stride N      (MLP1)
// MODE 3: out0 fp32 = res[m*384+n] + acc + bias0[n]                (MLP2 + residual)
template <int MODE, int MI, int KSTEPS>
__global__ __launch_bounds__(256) void k_gemmw(const u16* __restrict__ A, const u16* __restrict__ BT,
                                               int N,
                                               const float* __restrict__ bias0, const float* __restrict__ bias1,
                                               float* __restrict__ out0, u16* __restrict__ outb,
                                               u16* __restrict__ outb2, const float* __restrict__ res) {
  constexpr int K = KSTEPS * 32;
  const int tid = threadIdx.x;
  const int w = (blockIdx.x * 256 + tid) >> 6;
  const int lane = tid & 63, quad = lane >> 4, r15 = lane & 15;
  const int NT = N >> 6;
  const int mt = w / NT, nt = w - mt * NT;
  const int m0 = mt * (MI * 16), n0 = nt * 64;
  const u16* Ap = A + (size_t)(m0 + r15) * K + quad * 8;
  const u16* Bp = BT + (size_t)(n0 + r15) * K + quad * 8;
  f32x4 acc[MI][4] = {};
#pragma unroll 6
  for (int k0 = 0; k0 < K; k0 += 32) {
    bf16x8 af[MI], bw[4];
#pragma unroll
    for (int i = 0; i < MI; ++i) af[i] = *(const bf16x8*)(Ap + (size_t)(i * 16) * K + k0);
#pragma unroll
    for (int j = 0; j < 4; ++j) bw[j] = *(const bf16x8*)(Bp + (size_t)(j * 16) * K + k0);
#pragma unroll
    for (int i = 0; i < MI; ++i)
#pragma unroll
      for (int j = 0; j < 4; ++j)
        acc[i][j] = __builtin_amdgcn_mfma_f32_16x16x32_bf16(af[i], bw[j], acc[i][j], 0, 0, 0);
  }
#pragma unroll
  for (int i = 0; i < MI; ++i) {
#pragma unroll
    for (int j = 0; j < 4; ++j) {
#pragma unroll
      for (int rr = 0; rr < 4; ++rr) {
        int m = m0 + i * 16 + quad * 4 + rr;
        int n = n0 + j * 16 + r15;
        float v = acc[i][j][rr];
        if (MODE == 0) {
          v += bias0[n] + res[(size_t)(m % 196) * 384 + n];
          out0[(size_t)m * N + n] = v;
        } else if (MODE == 1) {
          if (n < 384) {
            outb[(size_t)m * 384 + n] = f2bf(v + bias0[n]);
          } else {
            float t = v + bias1[n - 384];
            outb2[(size_t)m * 384 + (n - 384)] = f2bf(1.f / (1.f + expf(-t)));
          }
        } else if (MODE == 2) {
          v += bias0[n];
          float gl = 0.5f * v * (1.f + tanhf(0.7978845608028654f * (v + 0.044715f * v * v * v)));
          outb[(size_t)m * N + n] = f2bf(gl);
        } else {
          out0[(size_t)m * 384 + n] = res[(size_t)m * 384 + n] + v + bias0[n];
        }
      }
    }
  }
}

// ---------------- gated depthwise-conv recurrence, T=8, fused; h += s (u,g bf16) ----------------
// block: (b, channel-group of 8); 1536 blocks; thread: channel c (8/block), pixels p = pg + 32k
__global__ __launch_bounds__(256) void k_recur(float* __restrict__ h, const u16* __restrict__ ubuf,
                                               const u16* __restrict__ gbuf, const float* __restrict__ kd) {
  __shared__ float sb[16 * 16 * 8];  // [y+1][x+1][c], zero halo, 8 KB
  const int tid = threadIdx.x;
  const int b = blockIdx.x, cg = blockIdx.y;
  const int c = tid & 7, pg = tid >> 3;  // pg in [0,32)
  const int cfull = cg * 8 + c;
  float kw[9];
#pragma unroll
  for (int q = 0; q < 9; ++q) kw[q] = kd[q * 384 + cfull];
  float gr[7], ur[7], sr[7];
#pragma unroll
  for (int kk = 0; kk < 7; ++kk) {
    int p = pg + kk * 32;
    bool ok = p < 196;
    size_t a = (size_t)(b * 196 + (ok ? p : 0)) * 384 + cfull;
    gr[kk] = ok ? bf2f(gbuf[a]) : 0.f;
    ur[kk] = ok ? bf2f(ubuf[a]) : 0.f;
    sr[kk] = 0.f;
  }
  for (int i = tid; i < 16 * 16 * 8; i += 256) sb[i] = 0.f;
  __syncthreads();
  for (int t = 0; t < 8; ++t) {
#pragma unroll
    for (int kk = 0; kk < 7; ++kk) {
      int p = pg + kk * 32;
      if (p < 196) {
        int y = p / 14, x = p - y * 14;
        int base = (y * 16 + x) * 8 + c;
        float conv = 0.f;
#pragma unroll
        for (int dy = 0; dy < 3; ++dy)
#pragma unroll
          for (int dx = 0; dx < 3; ++dx)
            conv += kw[dy * 3 + dx] * sb[base + (dy * 16 + dx) * 8];
        sr[kk] = gr[kk] * conv + (1.f - gr[kk]) * ur[kk];
      }
    }
    __syncthreads();
#pragma unroll
    for (int kk = 0; kk < 7; ++kk) {
      int p = pg + kk * 32;
      if (p < 196) {
        int y = p / 14, x = p - y * 14;
        sb[((y + 1) * 16 + (x + 1)) * 8 + c] = sr[kk];
      }
    }
    __syncthreads();
  }
#pragma unroll
  for (int kk = 0; kk < 7; ++kk) {
    int p = pg + kk * 32;
    if (p < 196) {
      size_t a = (size_t)(b * 196 + p) * 384 + cfull;
      h[a] += sr[kk];
    }
  }
}

// ---------------- pool: per-(b) spatial max over 196 tokens -> pooled fp32 (32,384) ----------------
__global__ __launch_bounds__(384) void k_pool(const u16* __restrict__ zf, float* __restrict__ pooled) {
  int b = blockIdx.x, c = threadIdx.x;
  const u16* zp = zf + (size_t)b * 196 * 384 + c;
  float mx = -3.4e38f;
  for (int t0 = 0; t0 < 196; t0 += 14) {
    float v[14];
#pragma unroll
    for (int j = 0; j < 14; ++j) v[j] = bf2f(zp[(t0 + j) * 384]);
#pragma unroll
    for (int j = 0; j < 14; ++j) mx = fmaxf(mx, v[j]);
  }
  pooled[b * 384 + c] = mx;
}

// ---------------- head GEMV: wave per (b,n); hwT is (1000,384) fp32 ----------------
__global__ __launch_bounds__(256) void k_head(const float* __restrict__ pooled, const float* __restrict__ hwT,
                                              const float* __restrict__ hb, float* __restrict__ out) {
  int w = (blockIdx.x * 256 + threadIdx.x) >> 6;  // 0..31999
  int lane = threadIdx.x & 63;
  int b = w / 1000, n = w - b * 1000;
  const float* pp = pooled + b * 384 + lane;
  const float* wp = hwT + (size_t)n * 384 + lane;
  float acc = 0.f;
#pragma unroll
  for (int j = 0; j < 6; ++j) acc += pp[j * 64] * wp[j * 64];
#pragma unroll
  for (int o = 1; o < 64; o <<= 1) acc += __shfl_xor(acc, o);
  if (lane == 0) out[w] = acc + hb[n];
}

extern "C" void kernel_launch(void* const* d_in, const int* in_sizes, int n_in,
                              void* d_out, int out_size, void* d_ws, size_t ws_size,
                              hipStream_t stream) {
  const float* x       = (const float*)d_in[0];
  const float* patch_w = (const float*)d_in[1];
  const float* patch_b = (const float*)d_in[2];
  const float* pos     = (const float*)d_in[3];
  const float* ln1_s   = (const float*)d_in[4];
  const float* ln1_b   = (const float*)d_in[5];
  const float* w_in    = (const float*)d_in[6];
  const float* b_in    = (const float*)d_in[7];
  const float* w_g     = (const float*)d_in[8];
  const float* b_g     = (const float*)d_in[9];
  const float* k_dw    = (const float*)d_in[10];
  const float* ln2_s   = (const float*)d_in[11];
  const float* ln2_b   = (const float*)d_in[12];
  const float* w1      = (const float*)d_in[13];
  const float* b1      = (const float*)d_in[14];
  const float* w2      = (const float*)d_in[15];
  const float* b2      = (const float*)d_in[16];
  const float* lnf_s   = (const float*)d_in[17];
  const float* lnf_b   = (const float*)d_in[18];
  const float* head_w  = (const float*)d_in[19];
  const float* head_b  = (const float*)d_in[20];
  float* out = (float*)d_out;

  const size_t M = 6272;
  const size_t SZ_TOK = M * 384;               // 2408448
  const size_t SZ_HID = M * 1536;              // 9633792
  const size_t WT_ELEMS = 17989632;            // patchT + 12*(ugT + w1T + w2T)
  const size_t NEED = SZ_TOK * 4 + SZ_TOK * 2 * 3 + SZ_HID * 2 + WT_ELEMS * 2;
  if (ws_size < NEED) return;

  char* ws = (char*)d_ws;
  float* h = (float*)ws;   ws += SZ_TOK * 4;
  u16* ub  = (u16*)ws;     ws += SZ_TOK * 2;
  u16* gb  = (u16*)ws;     ws += SZ_TOK * 2;
  u16* z   = (u16*)ws;     ws += SZ_TOK * 2;
  u16* hid = (u16*)ws;     ws += SZ_HID * 2;
  u16* pA  = hid;          // alias: patch A-matrix (M*768) fits in hid (M*1536), used before hid
  u16* wT  = (u16*)ws;
  float* pooled = (float*)ub;  // reuse ub at the end (free after last recur)
  float* hwT = (float*)hid;    // reuse hid at the end (free after last gemm3)

  // wT layout (elems): patchT[294912]; per d: WiT[147456] WgT[147456] w1T[589824] w2T[589824]
  const size_t PER_D = 1474560;
  u16* patchT = wT;
  u16* ugT0 = wT + 294912;
  u16* w1T0 = wT + 294912 + 294912;
  u16* w2T0 = wT + 294912 + 294912 + 589824;

  dim3 tb(32, 8);
  k_tcast<<<dim3(12, 24, 1), tb, 0, stream>>>(patch_w, patchT, 768, 384, (size_t)0, (size_t)0);
  k_tcast<<<dim3(12, 12, 12), tb, 0, stream>>>(w_in, ugT0, 384, 384, (size_t)147456, PER_D);
  k_tcast<<<dim3(12, 12, 12), tb, 0, stream>>>(w_g, ugT0 + 147456, 384, 384, (size_t)147456, PER_D);
  k_tcast<<<dim3(48, 12, 12), tb, 0, stream>>>(w1, w1T0, 384, 1536, (size_t)589824, PER_D);
  k_tcast<<<dim3(12, 48, 12), tb, 0, stream>>>(w2, w2T0, 1536, 384, (size_t)589824, PER_D);

  k_patch_extract<<<18816, 256, 0, stream>>>(x, pA);

  // patch embed GEMM: h = pA @ patch_w + patch_b + pos   (MI=2, K=768: 196x6 waves = 294 blocks)
  k_gemmw<0, 2, 24><<<294, 256, 0, stream>>>(pA, patchT, 384, patch_b, nullptr, h, nullptr, nullptr, pos);

  for (int d = 0; d < 12; ++d) {
    const u16* ugT = ugT0 + (size_t)d * PER_D;
    const u16* w1T = w1T0 + (size_t)d * PER_D;
    const u16* w2T = w2T0 + (size_t)d * PER_D;
    k_ln<<<1568, 256, 0, stream>>>(h, z, ln1_s + (size_t)d * 384, ln1_b + (size_t)d * 384);
    // u,g: MI=2, K=384, N=768: 196x12 waves = 588 blocks
    k_gemmw<1, 2, 12><<<588, 256, 0, stream>>>(z, ugT, 768, b_in + (size_t)d * 384,
                                               b_g + (size_t)d * 384, nullptr, ub, gb, nullptr);
    k_recur<<<dim3(32, 48), 256, 0, stream>>>(h, ub, gb, k_dw + (size_t)d * 3456);
    k_ln<<<1568, 256, 0, stream>>>(h, z, ln2_s + (size_t)d * 384, ln2_b + (size_t)d * 384);
    // MLP1: MI=4, K=384, N=1536: 98x24 waves = 588 blocks
    k_gemmw<2, 4, 12><<<588, 256, 0, stream>>>(z, w1T, 1536, b1 + (size_t)d * 1536,
                                               nullptr, nullptr, hid, nullptr, nullptr);
    // MLP2: MI=2, K=1536, N=384: 196x6 waves = 294 blocks
    k_gemmw<3, 2, 48><<<294, 256, 0, stream>>>(hid, w2T, 384, b2 + (size_t)d * 384,
                                               nullptr, h, nullptr, nullptr, h);
  }

  // transpose head_w (384,1000) -> hwT (1000,384) fp32 (hid buffer is free now)
  k_tcastf<<<dim3(32, 12), tb, 0, stream>>>(head_w, hwT, 384, 1000);

  k_ln<<<1568, 256, 0, stream>>>(h, z, lnf_s, lnf_b);
  k_pool<<<32, 384, 0, stream>>>(z, pooled);
  k_head<<<8000, 256, 0, stream>>>(pooled, hwT, head_b, out);
}

// Round 7
// 1537.698 us; speedup vs baseline: 1.5708x; 1.5708x over previous
//
#include <hip/hip_runtime.h>
#include <cstdint>
#include <cstddef>

#define DEV static __device__ __forceinline__

typedef unsigned short u16;
typedef unsigned int u32;
typedef __attribute__((ext_vector_type(8))) short short8;
typedef __attribute__((ext_vector_type(8))) __bf16 bf16x8;
typedef __attribute__((ext_vector_type(4))) float f32x4;

DEV u16 f2bf(float f) {
  u32 u = __builtin_bit_cast(u32, f);
  u32 r = (u + 0x7fffu + ((u >> 16) & 1u)) >> 16;
  return (u16)r;
}
DEV float bf2f(u16 h) { u32 u = ((u32)h) << 16; return __builtin_bit_cast(float, u); }
DEV u32 pack2(float a, float b) { return (u32)f2bf(a) | ((u32)f2bf(b) << 16); }

// async global->LDS, 16B per lane; lds base must be wave-uniform (dest = base + lane*16)
DEV void ld_lds16(const u16* g, u16* l) {
  __builtin_amdgcn_global_load_lds((const __attribute__((address_space(1))) void*)g,
                                   (__attribute__((address_space(3))) void*)l, 16, 0, 0);
}

// ---------------- weight transpose + cast: src fp32 (K,N) -> dst bf16 (N,K) ----------------
__global__ __launch_bounds__(256) void k_tcast(const float* __restrict__ src, u16* __restrict__ dst,
                                               int K, int N, size_t sStride, size_t dStride) {
  __shared__ float tl[32][33];
  int tx = threadIdx.x, ty = threadIdx.y;
  int n0 = blockIdx.x * 32, k0 = blockIdx.y * 32;
  src += (size_t)blockIdx.z * sStride;
  dst += (size_t)blockIdx.z * dStride;
#pragma unroll
  for (int i = 0; i < 4; ++i)
    tl[ty + i * 8][tx] = src[(size_t)(k0 + ty + i * 8) * N + n0 + tx];
  __syncthreads();
#pragma unroll
  for (int i = 0; i < 4; ++i)
    dst[(size_t)(n0 + ty + i * 8) * K + k0 + tx] = f2bf(tl[tx][ty + i * 8]);
}

// ---------------- fp32 transpose with N-guard: src (K,N) -> dst (N,K); K % 32 == 0 ----------------
__global__ __launch_bounds__(256) void k_tcastf(const float* __restrict__ src, float* __restrict__ dst,
                                                int K, int N) {
  __shared__ float tl[32][33];
  int tx = threadIdx.x, ty = threadIdx.y;
  int n0 = blockIdx.x * 32, k0 = blockIdx.y * 32;
#pragma unroll
  for (int i = 0; i < 4; ++i)
    if (n0 + tx < N) tl[ty + i * 8][tx] = src[(size_t)(k0 + ty + i * 8) * N + n0 + tx];
  __syncthreads();
#pragma unroll
  for (int i = 0; i < 4; ++i)
    if (n0 + ty + i * 8 < N) dst[(size_t)(n0 + ty + i * 8) * K + k0 + tx] = tl[tx][ty + i * 8];
}

// ---------------- patch extraction: x (B,224,224,3) -> pA bf16 (6272, 768) ----------------
__global__ __launch_bounds__(256) void k_patch_extract(const float* __restrict__ x, u16* __restrict__ pA) {
  int idx = blockIdx.x * 256 + threadIdx.x;  // < 6272*768
  int token = idx / 768, kk = idx - token * 768;
  int b = token / 196, t = token - b * 196;
  int gy = t / 14, gx = t - gy * 14;
  int py = kk / 48, rem = kk - py * 48;
  int px = rem / 3, ch = rem - px * 3;
  size_t s = ((size_t)(b * 224 + gy * 16 + py) * 224 + (gx * 16 + px)) * 3 + ch;
  pA[idx] = f2bf(x[s]);
}

// ---------------- LayerNorm: h fp32 (6272,384) -> z bf16; wave/token, lane-contiguous ----------------
__global__ __launch_bounds__(256) void k_ln(const float* __restrict__ h, u16* __restrict__ z,
                                            const float* __restrict__ sc, const float* __restrict__ bi) {
  int wave = threadIdx.x >> 6, lane = threadIdx.x & 63;
  int token = blockIdx.x * 4 + wave;
  const float* hp = h + (size_t)token * 384 + lane * 6;
  float2 v0 = *(const float2*)hp;
  float2 v1 = *(const float2*)(hp + 2);
  float2 v2 = *(const float2*)(hp + 4);
  float sum = v0.x + v0.y + v1.x + v1.y + v2.x + v2.y;
  float sq = v0.x * v0.x + v0.y * v0.y + v1.x * v1.x + v1.y * v1.y + v2.x * v2.x + v2.y * v2.y;
#pragma unroll
  for (int o = 1; o < 64; o <<= 1) { sum += __shfl_xor(sum, o); sq += __shfl_xor(sq, o); }
  float mean = sum * (1.f / 384.f);
  float var = sq * (1.f / 384.f) - mean * mean;
  float rstd = rsqrtf(var + 1e-6f);
  const float* scp = sc + lane * 6;
  const float* bip = bi + lane * 6;
  float2 s0 = *(const float2*)scp, s1 = *(const float2*)(scp + 2), s2 = *(const float2*)(scp + 4);
  float2 b0 = *(const float2*)bip, b1 = *(const float2*)(bip + 2), b2 = *(const float2*)(bip + 4);
  u16* zp = z + (size_t)token * 384 + lane * 6;
  *(u32*)(zp)     = pack2((v0.x - mean) * rstd * s0.x + b0.x, (v0.y - mean) * rstd * s0.y + b0.y);
  *(u32*)(zp + 2) = pack2((v1.x - mean) * rstd * s1.x + b1.x, (v1.y - mean) * rstd * s1.y + b1.y);
  *(u32*)(zp + 4) = pack2((v2.x - mean) * rstd * s2.x + b2.x, (v2.y - mean) * rstd * s2.y + b2.y);
}

// ---------------- GEMM: C = A(M,K)bf16 * BT(N,K)bf16, (MI*32)x128 tile, 4 waves ----------------
// MI=2: 64x128 tile (wave = 32x64), LDS 12 KB  [best-measured config r3/r4]
// MODE 0: out0 fp32 = acc + bias0[n] + res[(m%196)*384+n]          (patch embed + pos)
// MODE 1: n<384 -> outb = bf16(acc+bias0[n]); else outb2 = bf16(sigmoid(acc+bias1[n-384]))  (u,g)
// MODE 2: outb bf16 = gelu_tanh(acc + bias0[n])                    (MLP1)
// MODE 3: out0 fp32 = res[m*384+n] + acc + bias0[n]                (MLP2 + residual)
template <int MODE, int MI>
__global__ __launch_bounds__(256) void k_gemm(const u16* __restrict__ A, const u16* __restrict__ BT,
                                              int K, int N,
                                              const float* __restrict__ bias0, const float* __restrict__ bias1,
                                              float* __restrict__ out0, u16* __restrict__ outb,
                                              u16* __restrict__ outb2, const float* __restrict__ res) {
  constexpr int TM = MI * 32;
  // LDS layout is lane-contiguous: byte addr = tid*16 (+ st*4096) -> row-major (rows x 32) u16
  __shared__ alignas(16) u16 As[TM * 32];
  __shared__ alignas(16) u16 Bs[128 * 32];
  const int tid = threadIdx.x;
  const int tm = blockIdx.y * TM, tn = blockIdx.x * 128;
  const int lane = tid & 63, wave = tid >> 6;
  const int wy = (wave >> 1) * (MI * 16), wx = (wave & 1) * 64;
  const int quad = lane >> 4, r15 = lane & 15;
  const int rowA = tid >> 2, offA = (tid & 3) * 8;
  const u16* Ab = A + (size_t)(tm + (rowA < TM ? rowA : 0)) * K + offA;
  const u16* Bb = BT + (size_t)(tn + rowA) * K + offA;
  u16* AsW = As + wave * 512;  // wave-uniform LDS base (u16 elems; *2 = bytes)
  u16* BsW = Bs + wave * 512;
  f32x4 acc[MI][4] = {};
  for (int k0 = 0; k0 < K; k0 += 32) {
#pragma unroll
    for (int st = 0; st < (TM + 63) / 64; ++st)
      if (TM >= 64 || tid < TM * 4)  // wave-uniform guard
        ld_lds16(Ab + (size_t)st * 64 * K + k0, AsW + st * 2048);
#pragma unroll
    for (int st = 0; st < 2; ++st)
      ld_lds16(Bb + (size_t)st * 64 * K + k0, BsW + st * 2048);
    __syncthreads();
    bf16x8 af[MI], bw[4];
#pragma unroll
    for (int i = 0; i < MI; ++i) af[i] = *(const bf16x8*)&As[(wy + i * 16 + r15) * 32 + quad * 8];
#pragma unroll
    for (int j = 0; j < 4; ++j) bw[j] = *(const bf16x8*)&Bs[(wx + j * 16 + r15) * 32 + quad * 8];
#pragma unroll
    for (int i = 0; i < MI; ++i)
#pragma unroll
      for (int j = 0; j < 4; ++j)
        acc[i][j] = __builtin_amdgcn_mfma_f32_16x16x32_bf16(af[i], bw[j], acc[i][j], 0, 0, 0);
    __syncthreads();
  }
#pragma unroll
  for (int i = 0; i < MI; ++i) {
#pragma unroll
    for (int j = 0; j < 4; ++j) {
#pragma unroll
      for (int rr = 0; rr < 4; ++rr) {
        int m = tm + wy + i * 16 + quad * 4 + rr;
        int n = tn + wx + j * 16 + r15;
        float v = acc[i][j][rr];
        if (MODE == 0) {
          v += bias0[n] + res[(size_t)(m % 196) * 384 + n];
          out0[(size_t)m * N + n] = v;
        } else if (MODE == 1) {
          if (n < 384) {
            outb[(size_t)m * 384 + n] = f2bf(v + bias0[n]);
          } else {
            float t = v + bias1[n - 384];
            outb2[(size_t)m * 384 + (n - 384)] = f2bf(1.f / (1.f + expf(-t)));
          }
        } else if (MODE == 2) {
          v += bias0[n];
          float gl = 0.5f * v * (1.f + tanhf(0.7978845608028654f * (v + 0.044715f * v * v * v)));
          outb[(size_t)m * N + n] = f2bf(gl);
        } else {
          out0[(size_t)m * 384 + n] = res[(size_t)m * 384 + n] + v + bias0[n];
        }
      }
    }
  }
}

// ---------------- gated depthwise-conv recurrence, T=8, fused; h += s (u,g bf16) ----------------
// block: (b, channel-group of 8); 1536 blocks; thread: channel c (8/block), pixels p = pg + 32k
__global__ __launch_bounds__(256) void k_recur(float* __restrict__ h, const u16* __restrict__ ubuf,
                                               const u16* __restrict__ gbuf, const float* __restrict__ kd) {
  __shared__ float sb[16 * 16 * 8];  // [y+1][x+1][c], zero halo, 8 KB
  const int tid = threadIdx.x;
  const int b = blockIdx.x, cg = blockIdx.y;
  const int c = tid & 7, pg = tid >> 3;  // pg in [0,32)
  const int cfull = cg * 8 + c;
  float kw[9];
#pragma unroll
  for (int q = 0; q < 9; ++q) kw[q] = kd[q * 384 + cfull];
  float gr[7], ur[7], sr[7];
#pragma unroll
  for (int kk = 0; kk < 7; ++kk) {
    int p = pg + kk * 32;
    bool ok = p < 196;
    size_t a = (size_t)(b * 196 + (ok ? p : 0)) * 384 + cfull;
    gr[kk] = ok ? bf2f(gbuf[a]) : 0.f;
    ur[kk] = ok ? bf2f(ubuf[a]) : 0.f;
    sr[kk] = 0.f;
  }
  for (int i = tid; i < 16 * 16 * 8; i += 256) sb[i] = 0.f;
  __syncthreads();
  for (int t = 0; t < 8; ++t) {
#pragma unroll
    for (int kk = 0; kk < 7; ++kk) {
      int p = pg + kk * 32;
      if (p < 196) {
        int y = p / 14, x = p - y * 14;
        int base = (y * 16 + x) * 8 + c;
        float conv = 0.f;
#pragma unroll
        for (int dy = 0; dy < 3; ++dy)
#pragma unroll
          for (int dx = 0; dx < 3; ++dx)
            conv += kw[dy * 3 + dx] * sb[base + (dy * 16 + dx) * 8];
        sr[kk] = gr[kk] * conv + (1.f - gr[kk]) * ur[kk];
      }
    }
    __syncthreads();
#pragma unroll
    for (int kk = 0; kk < 7; ++kk) {
      int p = pg + kk * 32;
      if (p < 196) {
        int y = p / 14, x = p - y * 14;
        sb[((y + 1) * 16 + (x + 1)) * 8 + c] = sr[kk];
      }
    }
    __syncthreads();
  }
#pragma unroll
  for (int kk = 0; kk < 7; ++kk) {
    int p = pg + kk * 32;
    if (p < 196) {
      size_t a = (size_t)(b * 196 + p) * 384 + cfull;
      h[a] += sr[kk];
    }
  }
}

// ---------------- pool: per-(b) spatial max over 196 tokens -> pooled fp32 (32,384) ----------------
__global__ __launch_bounds__(384) void k_pool(const u16* __restrict__ zf, float* __restrict__ pooled) {
  int b = blockIdx.x, c = threadIdx.x;
  const u16* zp = zf + (size_t)b * 196 * 384 + c;
  float mx = -3.4e38f;
  for (int t0 = 0; t0 < 196; t0 += 14) {
    float v[14];
#pragma unroll
    for (int j = 0; j < 14; ++j) v[j] = bf2f(zp[(t0 + j) * 384]);
#pragma unroll
    for (int j = 0; j < 14; ++j) mx = fmaxf(mx, v[j]);
  }
  pooled[b * 384 + c] = mx;
}

// ---------------- head GEMV: wave per (b,n); hwT is (1000,384) fp32 ----------------
__global__ __launch_bounds__(256) void k_head(const float* __restrict__ pooled, const float* __restrict__ hwT,
                                              const float* __restrict__ hb, float* __restrict__ out) {
  int w = (blockIdx.x * 256 + threadIdx.x) >> 6;  // 0..31999
  int lane = threadIdx.x & 63;
  int b = w / 1000, n = w - b * 1000;
  const float* pp = pooled + b * 384 + lane;
  const float* wp = hwT + (size_t)n * 384 + lane;
  float acc = 0.f;
#pragma unroll
  for (int j = 0; j < 6; ++j) acc += pp[j * 64] * wp[j * 64];
#pragma unroll
  for (int o = 1; o < 64; o <<= 1) acc += __shfl_xor(acc, o);
  if (lane == 0) out[w] = acc + hb[n];
}

extern "C" void kernel_launch(void* const* d_in, const int* in_sizes, int n_in,
                              void* d_out, int out_size, void* d_ws, size_t ws_size,
                              hipStream_t stream) {
  const float* x       = (const float*)d_in[0];
  const float* patch_w = (const float*)d_in[1];
  const float* patch_b = (const float*)d_in[2];
  const float* pos     = (const float*)d_in[3];
  const float* ln1_s   = (const float*)d_in[4];
  const float* ln1_b   = (const float*)d_in[5];
  const float* w_in    = (const float*)d_in[6];
  const float* b_in    = (const float*)d_in[7];
  const float* w_g     = (const float*)d_in[8];
  const float* b_g     = (const float*)d_in[9];
  const float* k_dw    = (const float*)d_in[10];
  const float* ln2_s   = (const float*)d_in[11];
  const float* ln2_b   = (const float*)d_in[12];
  const float* w1      = (const float*)d_in[13];
  const float* b1      = (const float*)d_in[14];
  const float* w2      = (const float*)d_in[15];
  const float* b2      = (const float*)d_in[16];
  const float* lnf_s   = (const float*)d_in[17];
  const float* lnf_b   = (const float*)d_in[18];
  const float* head_w  = (const float*)d_in[19];
  const float* head_b  = (const float*)d_in[20];
  float* out = (float*)d_out;

  const size_t M = 6272;
  const size_t SZ_TOK = M * 384;               // 2408448
  const size_t SZ_HID = M * 1536;              // 9633792
  const size_t WT_ELEMS = 17989632;            // patchT + 12*(ugT + w1T + w2T)
  const size_t NEED = SZ_TOK * 4 + SZ_TOK * 2 * 3 + SZ_HID * 2 + WT_ELEMS * 2;
  if (ws_size < NEED) return;

  char* ws = (char*)d_ws;
  float* h = (float*)ws;   ws += SZ_TOK * 4;
  u16* ub  = (u16*)ws;     ws += SZ_TOK * 2;
  u16* gb  = (u16*)ws;     ws += SZ_TOK * 2;
  u16* z   = (u16*)ws;     ws += SZ_TOK * 2;
  u16* hid = (u16*)ws;     ws += SZ_HID * 2;
  u16* pA  = hid;          // alias: patch A-matrix (M*768) fits in hid (M*1536), used before hid
  u16* wT  = (u16*)ws;
  float* pooled = (float*)ub;  // reuse ub at the end (free after last recur)
  float* hwT = (float*)hid;    // reuse hid at the end (free after last gemm3)

  // wT layout (elems): patchT[294912]; per d: WiT[147456] WgT[147456] w1T[589824] w2T[589824]
  const size_t PER_D = 1474560;
  u16* patchT = wT;
  u16* ugT0 = wT + 294912;
  u16* w1T0 = wT + 294912 + 294912;
  u16* w2T0 = wT + 294912 + 294912 + 589824;

  dim3 tb(32, 8);
  k_tcast<<<dim3(12, 24, 1), tb, 0, stream>>>(patch_w, patchT, 768, 384, (size_t)0, (size_t)0);
  k_tcast<<<dim3(12, 12, 12), tb, 0, stream>>>(w_in, ugT0, 384, 384, (size_t)147456, PER_D);
  k_tcast<<<dim3(12, 12, 12), tb, 0, stream>>>(w_g, ugT0 + 147456, 384, 384, (size_t)147456, PER_D);
  k_tcast<<<dim3(48, 12, 12), tb, 0, stream>>>(w1, w1T0, 384, 1536, (size_t)589824, PER_D);
  k_tcast<<<dim3(12, 48, 12), tb, 0, stream>>>(w2, w2T0, 1536, 384, (size_t)589824, PER_D);

  k_patch_extract<<<18816, 256, 0, stream>>>(x, pA);

  // patch embed GEMM: h = pA @ patch_w + patch_b + pos  (64x128 tiles: 3x98)
  k_gemm<0, 2><<<dim3(3, 98), 256, 0, stream>>>(pA, patchT, 768, 384, patch_b, nullptr,
                                                h, nullptr, nullptr, pos);

  for (int d = 0; d < 12; ++d) {
    const u16* ugT = ugT0 + (size_t)d * PER_D;
    const u16* w1T = w1T0 + (size_t)d * PER_D;
    const u16* w2T = w2T0 + (size_t)d * PER_D;
    k_ln<<<1568, 256, 0, stream>>>(h, z, ln1_s + (size_t)d * 384, ln1_b + (size_t)d * 384);
    k_gemm<1, 2><<<dim3(6, 98), 256, 0, stream>>>(z, ugT, 384, 768, b_in + (size_t)d * 384,
                                                  b_g + (size_t)d * 384, nullptr, ub, gb, nullptr);
    k_recur<<<dim3(32, 48), 256, 0, stream>>>(h, ub, gb, k_dw + (size_t)d * 3456);
    k_ln<<<1568, 256, 0, stream>>>(h, z, ln2_s + (size_t)d * 384, ln2_b + (size_t)d * 384);
    k_gemm<2, 2><<<dim3(12, 98), 256, 0, stream>>>(z, w1T, 384, 1536, b1 + (size_t)d * 1536,
                                                   nullptr, nullptr, hid, nullptr, nullptr);
    k_gemm<3, 2><<<dim3(3, 98), 256, 0, stream>>>(hid, w2T, 1536, 384, b2 + (size_t)d * 384,
                                                  nullptr, h, nullptr, nullptr, h);
  }

  // transpose head_w (384,1000) -> hwT (1000,384) fp32 (hid buffer is free now)
  k_tcastf<<<dim3(32, 12), tb, 0, stream>>>(head_w, hwT, 384, 1000);

  k_ln<<<1568, 256, 0, stream>>>(h, z, lnf_s, lnf_b);
  k_pool<<<32, 384, 0, stream>>>(z, pooled);
  k_head<<<8000, 256, 0, stream>>>(pooled, hwT, head_b, out);
}

// Round 8
// 1414.450 us; speedup vs baseline: 1.7077x; 1.0871x over previous
//
#include <hip/hip_runtime.h>
#include <cstdint>
#include <cstddef>

#define DEV static __device__ __forceinline__

typedef unsigned short u16;
typedef unsigned int u32;
typedef __attribute__((ext_vector_type(8))) short short8;
typedef __attribute__((ext_vector_type(8))) __bf16 bf16x8;
typedef __attribute__((ext_vector_type(4))) float f32x4;

DEV u16 f2bf(float f) {
  u32 u = __builtin_bit_cast(u32, f);
  u32 r = (u + 0x7fffu + ((u >> 16) & 1u)) >> 16;
  return (u16)r;
}
DEV float bf2f(u16 h) { u32 u = ((u32)h) << 16; return __builtin_bit_cast(float, u); }
DEV u32 pack2(float a, float b) { return (u32)f2bf(a) | ((u32)f2bf(b) << 16); }

// async global->LDS, 16B per lane; lds base must be wave-uniform (dest = base + lane*16)
DEV void ld_lds16(const u16* g, u16* l) {
  __builtin_amdgcn_global_load_lds((const __attribute__((address_space(1))) void*)g,
                                   (__attribute__((address_space(3))) void*)l, 16, 0, 0);
}

// ---------------- weight transpose + cast: src fp32 (K,N) -> dst bf16 (N,K) ----------------
__global__ __launch_bounds__(256) void k_tcast(const float* __restrict__ src, u16* __restrict__ dst,
                                               int K, int N, size_t sStride, size_t dStride) {
  __shared__ float tl[32][33];
  int tx = threadIdx.x, ty = threadIdx.y;
  int n0 = blockIdx.x * 32, k0 = blockIdx.y * 32;
  src += (size_t)blockIdx.z * sStride;
  dst += (size_t)blockIdx.z * dStride;
#pragma unroll
  for (int i = 0; i < 4; ++i)
    tl[ty + i * 8][tx] = src[(size_t)(k0 + ty + i * 8) * N + n0 + tx];
  __syncthreads();
#pragma unroll
  for (int i = 0; i < 4; ++i)
    dst[(size_t)(n0 + ty + i * 8) * K + k0 + tx] = f2bf(tl[tx][ty + i * 8]);
}

// ---------------- fp32 transpose with N-guard: src (K,N) -> dst (N,K); K % 32 == 0 ----------------
__global__ __launch_bounds__(256) void k_tcastf(const float* __restrict__ src, float* __restrict__ dst,
                                                int K, int N) {
  __shared__ float tl[32][33];
  int tx = threadIdx.x, ty = threadIdx.y;
  int n0 = blockIdx.x * 32, k0 = blockIdx.y * 32;
#pragma unroll
  for (int i = 0; i < 4; ++i)
    if (n0 + tx < N) tl[ty + i * 8][tx] = src[(size_t)(k0 + ty + i * 8) * N + n0 + tx];
  __syncthreads();
#pragma unroll
  for (int i = 0; i < 4; ++i)
    if (n0 + ty + i * 8 < N) dst[(size_t)(n0 + ty + i * 8) * K + k0 + tx] = tl[tx][ty + i * 8];
}

// ---------------- patch extraction: x (B,224,224,3) -> pA bf16 (6272, 768) ----------------
__global__ __launch_bounds__(256) void k_patch_extract(const float* __restrict__ x, u16* __restrict__ pA) {
  int idx = blockIdx.x * 256 + threadIdx.x;  // < 6272*768
  int token = idx / 768, kk = idx - token * 768;
  int b = token / 196, t = token - b * 196;
  int gy = t / 14, gx = t - gy * 14;
  int py = kk / 48, rem = kk - py * 48;
  int px = rem / 3, ch = rem - px * 3;
  size_t s = ((size_t)(b * 224 + gy * 16 + py) * 224 + (gx * 16 + px)) * 3 + ch;
  pA[idx] = f2bf(x[s]);
}

// ---------------- LayerNorm: h fp32 (6272,384) -> z bf16; wave/token, lane-contiguous ----------------
__global__ __launch_bounds__(256) void k_ln(const float* __restrict__ h, u16* __restrict__ z,
                                            const float* __restrict__ sc, const float* __restrict__ bi) {
  int wave = threadIdx.x >> 6, lane = threadIdx.x & 63;
  int token = blockIdx.x * 4 + wave;
  const float* hp = h + (size_t)token * 384 + lane * 6;
  float2 v0 = *(const float2*)hp;
  float2 v1 = *(const float2*)(hp + 2);
  float2 v2 = *(const float2*)(hp + 4);
  float sum = v0.x + v0.y + v1.x + v1.y + v2.x + v2.y;
  float sq = v0.x * v0.x + v0.y * v0.y + v1.x * v1.x + v1.y * v1.y + v2.x * v2.x + v2.y * v2.y;
#pragma unroll
  for (int o = 1; o < 64; o <<= 1) { sum += __shfl_xor(sum, o); sq += __shfl_xor(sq, o); }
  float mean = sum * (1.f / 384.f);
  float var = sq * (1.f / 384.f) - mean * mean;
  float rstd = rsqrtf(var + 1e-6f);
  const float* scp = sc + lane * 6;
  const float* bip = bi + lane * 6;
  float2 s0 = *(const float2*)scp, s1 = *(const float2*)(scp + 2), s2 = *(const float2*)(scp + 4);
  float2 b0 = *(const float2*)bip, b1 = *(const float2*)(bip + 2), b2 = *(const float2*)(bip + 4);
  u16* zp = z + (size_t)token * 384 + lane * 6;
  *(u32*)(zp)     = pack2((v0.x - mean) * rstd * s0.x + b0.x, (v0.y - mean) * rstd * s0.y + b0.y);
  *(u32*)(zp + 2) = pack2((v1.x - mean) * rstd * s1.x + b1.x, (v1.y - mean) * rstd * s1.y + b1.y);
  *(u32*)(zp + 4) = pack2((v2.x - mean) * rstd * s2.x + b2.x, (v2.y - mean) * rstd * s2.y + b2.y);
}

// ---------------- GEMM: C = A(M,K)bf16 * BT(N,K)bf16, 64x128 tile, 4 waves ----------------
// BK=64 (two 32-wide ping-pong panels -> half the barrier drains), xor-swizzled LDS slots
// (slot = quad ^ ((row>>1)&3)) so ds_read_b128 is 2-way max (free). Staging permutes SOURCE
// columns, preserving the global_load_lds lane-contiguity contract.
// MODE 0: out0 fp32 = acc + bias0[n] + res[(m%196)*384+n]          (patch embed + pos)
// MODE 1: n<384 -> outb = bf16(acc+bias0[n]); else outb2 = bf16(sigmoid(acc+bias1[n-384]))  (u,g)
// MODE 2: outb bf16 = gelu_tanh(acc + bias0[n])                    (MLP1)
// MODE 3: out0 fp32 = res[m*384+n] + acc + bias0[n]                (MLP2 + residual)
template <int MODE>
__global__ __launch_bounds__(256) void k_gemm(const u16* __restrict__ A, const u16* __restrict__ BT,
                                              int K, int N,
                                              const float* __restrict__ bias0, const float* __restrict__ bias1,
                                              float* __restrict__ out0, u16* __restrict__ outb,
                                              u16* __restrict__ outb2, const float* __restrict__ res) {
  constexpr int TM = 64;
  __shared__ alignas(16) u16 As[2][TM * 32];   // 2 x 4 KB
  __shared__ alignas(16) u16 Bs[2][128 * 32];  // 2 x 8 KB
  const int tid = threadIdx.x;
  const int tm = blockIdx.y * TM, tn = blockIdx.x * 128;
  const int lane = tid & 63, wave = tid >> 6;
  const int wy = (wave >> 1) * 32, wx = (wave & 1) * 64;
  const int quad = lane >> 4, r15 = lane & 15;
  const int swz = (quad ^ ((r15 >> 1) & 3)) * 8;  // read slot (u16 elems)
  // staging: thread covers (row = tid>>2, 16B slot = tid&3); source col is swizzled
  const int rowS = tid >> 2;
  const int colS = (((tid & 3) ^ ((rowS >> 1) & 3))) * 8;
  const u16* Ab = A + (size_t)(tm + rowS) * K + colS;
  const u16* Bb = BT + (size_t)(tn + rowS) * K + colS;  // pass st adds 64 rows; key((row+64)>>1) == key ✓
  u16* AsW0 = &As[0][wave * 512];
  u16* AsW1 = &As[1][wave * 512];
  u16* BsW0 = &Bs[0][wave * 512];
  u16* BsW1 = &Bs[1][wave * 512];
  f32x4 acc[2][4] = {};
  for (int k0 = 0; k0 < K; k0 += 64) {
    ld_lds16(Ab + k0, AsW0);
    ld_lds16(Ab + k0 + 32, AsW1);
#pragma unroll
    for (int st = 0; st < 2; ++st) {
      ld_lds16(Bb + (size_t)st * 64 * K + k0, BsW0 + st * 2048);
      ld_lds16(Bb + (size_t)st * 64 * K + k0 + 32, BsW1 + st * 2048);
    }
    __syncthreads();
#pragma unroll
    for (int p = 0; p < 2; ++p) {
      bf16x8 af[2], bw[4];
#pragma unroll
      for (int i = 0; i < 2; ++i) af[i] = *(const bf16x8*)&As[p][(wy + i * 16 + r15) * 32 + swz];
#pragma unroll
      for (int j = 0; j < 4; ++j) bw[j] = *(const bf16x8*)&Bs[p][(wx + j * 16 + r15) * 32 + swz];
#pragma unroll
      for (int i = 0; i < 2; ++i)
#pragma unroll
        for (int j = 0; j < 4; ++j)
          acc[i][j] = __builtin_amdgcn_mfma_f32_16x16x32_bf16(af[i], bw[j], acc[i][j], 0, 0, 0);
    }
    __syncthreads();
  }
#pragma unroll
  for (int i = 0; i < 2; ++i) {
#pragma unroll
    for (int j = 0; j < 4; ++j) {
#pragma unroll
      for (int rr = 0; rr < 4; ++rr) {
        int m = tm + wy + i * 16 + quad * 4 + rr;
        int n = tn + wx + j * 16 + r15;
        float v = acc[i][j][rr];
        if (MODE == 0) {
          v += bias0[n] + res[(size_t)(m % 196) * 384 + n];
          out0[(size_t)m * N + n] = v;
        } else if (MODE == 1) {
          if (n < 384) {
            outb[(size_t)m * 384 + n] = f2bf(v + bias0[n]);
          } else {
            float t = v + bias1[n - 384];
            outb2[(size_t)m * 384 + (n - 384)] = f2bf(1.f / (1.f + expf(-t)));
          }
        } else if (MODE == 2) {
          v += bias0[n];
          float gl = 0.5f * v * (1.f + tanhf(0.7978845608028654f * (v + 0.044715f * v * v * v)));
          outb[(size_t)m * N + n] = f2bf(gl);
        } else {
          out0[(size_t)m * 384 + n] = res[(size_t)m * 384 + n] + v + bias0[n];
        }
      }
    }
  }
}

// ---------------- gated depthwise-conv recurrence, T=8, fused; h += s (u,g bf16) ----------------
// block: (b, channel-group of 8); 1536 blocks; thread: channel c (8/block), pixels p = pg + 32k
__global__ __launch_bounds__(256) void k_recur(float* __restrict__ h, const u16* __restrict__ ubuf,
                                               const u16* __restrict__ gbuf, const float* __restrict__ kd) {
  __shared__ float sb[16 * 16 * 8];  // [y+1][x+1][c], zero halo, 8 KB
  const int tid = threadIdx.x;
  const int b = blockIdx.x, cg = blockIdx.y;
  const int c = tid & 7, pg = tid >> 3;  // pg in [0,32)
  const int cfull = cg * 8 + c;
  float kw[9];
#pragma unroll
  for (int q = 0; q < 9; ++q) kw[q] = kd[q * 384 + cfull];
  float gr[7], ur[7], sr[7];
#pragma unroll
  for (int kk = 0; kk < 7; ++kk) {
    int p = pg + kk * 32;
    bool ok = p < 196;
    size_t a = (size_t)(b * 196 + (ok ? p : 0)) * 384 + cfull;
    gr[kk] = ok ? bf2f(gbuf[a]) : 0.f;
    ur[kk] = ok ? bf2f(ubuf[a]) : 0.f;
    sr[kk] = 0.f;
  }
  for (int i = tid; i < 16 * 16 * 8; i += 256) sb[i] = 0.f;
  __syncthreads();
  for (int t = 0; t < 8; ++t) {
#pragma unroll
    for (int kk = 0; kk < 7; ++kk) {
      int p = pg + kk * 32;
      if (p < 196) {
        int y = p / 14, x = p - y * 14;
        int base = (y * 16 + x) * 8 + c;
        float conv = 0.f;
#pragma unroll
        for (int dy = 0; dy < 3; ++dy)
#pragma unroll
          for (int dx = 0; dx < 3; ++dx)
            conv += kw[dy * 3 + dx] * sb[base + (dy * 16 + dx) * 8];
        sr[kk] = gr[kk] * conv + (1.f - gr[kk]) * ur[kk];
      }
    }
    __syncthreads();
#pragma unroll
    for (int kk = 0; kk < 7; ++kk) {
      int p = pg + kk * 32;
      if (p < 196) {
        int y = p / 14, x = p - y * 14;
        sb[((y + 1) * 16 + (x + 1)) * 8 + c] = sr[kk];
      }
    }
    __syncthreads();
  }
#pragma unroll
  for (int kk = 0; kk < 7; ++kk) {
    int p = pg + kk * 32;
    if (p < 196) {
      size_t a = (size_t)(b * 196 + p) * 384 + cfull;
      h[a] += sr[kk];
    }
  }
}

// ---------------- pool: per-(b) spatial max over 196 tokens -> pooled fp32 (32,384) ----------------
__global__ __launch_bounds__(384) void k_pool(const u16* __restrict__ zf, float* __restrict__ pooled) {
  int b = blockIdx.x, c = threadIdx.x;
  const u16* zp = zf + (size_t)b * 196 * 384 + c;
  float mx = -3.4e38f;
  for (int t0 = 0; t0 < 196; t0 += 14) {
    float v[14];
#pragma unroll
    for (int j = 0; j < 14; ++j) v[j] = bf2f(zp[(t0 + j) * 384]);
#pragma unroll
    for (int j = 0; j < 14; ++j) mx = fmaxf(mx, v[j]);
  }
  pooled[b * 384 + c] = mx;
}

// ---------------- head GEMV: wave per (b,n); hwT is (1000,384) fp32 ----------------
__global__ __launch_bounds__(256) void k_head(const float* __restrict__ pooled, const float* __restrict__ hwT,
                                              const float* __restrict__ hb, float* __restrict__ out) {
  int w = (blockIdx.x * 256 + threadIdx.x) >> 6;  // 0..31999
  int lane = threadIdx.x & 63;
  int b = w / 1000, n = w - b * 1000;
  const float* pp = pooled + b * 384 + lane;
  const float* wp = hwT + (size_t)n * 384 + lane;
  float acc = 0.f;
#pragma unroll
  for (int j = 0; j < 6; ++j) acc += pp[j * 64] * wp[j * 64];
#pragma unroll
  for (int o = 1; o < 64; o <<= 1) acc += __shfl_xor(acc, o);
  if (lane == 0) out[w] = acc + hb[n];
}

extern "C" void kernel_launch(void* const* d_in, const int* in_sizes, int n_in,
                              void* d_out, int out_size, void* d_ws, size_t ws_size,
                              hipStream_t stream) {
  const float* x       = (const float*)d_in[0];
  const float* patch_w = (const float*)d_in[1];
  const float* patch_b = (const float*)d_in[2];
  const float* pos     = (const float*)d_in[3];
  const float* ln1_s   = (const float*)d_in[4];
  const float* ln1_b   = (const float*)d_in[5];
  const float* w_in    = (const float*)d_in[6];
  const float* b_in    = (const float*)d_in[7];
  const float* w_g     = (const float*)d_in[8];
  const float* b_g     = (const float*)d_in[9];
  const float* k_dw    = (const float*)d_in[10];
  const float* ln2_s   = (const float*)d_in[11];
  const float* ln2_b   = (const float*)d_in[12];
  const float* w1      = (const float*)d_in[13];
  const float* b1      = (const float*)d_in[14];
  const float* w2      = (const float*)d_in[15];
  const float* b2      = (const float*)d_in[16];
  const float* lnf_s   = (const float*)d_in[17];
  const float* lnf_b   = (const float*)d_in[18];
  const float* head_w  = (const float*)d_in[19];
  const float* head_b  = (const float*)d_in[20];
  float* out = (float*)d_out;

  const size_t M = 6272;
  const size_t SZ_TOK = M * 384;               // 2408448
  const size_t SZ_HID = M * 1536;              // 9633792
  const size_t WT_ELEMS = 17989632;            // patchT + 12*(ugT + w1T + w2T)
  const size_t NEED = SZ_TOK * 4 + SZ_TOK * 2 * 3 + SZ_HID * 2 + WT_ELEMS * 2;
  if (ws_size < NEED) return;

  char* ws = (char*)d_ws;
  float* h = (float*)ws;   ws += SZ_TOK * 4;
  u16* ub  = (u16*)ws;     ws += SZ_TOK * 2;
  u16* gb  = (u16*)ws;     ws += SZ_TOK * 2;
  u16* z   = (u16*)ws;     ws += SZ_TOK * 2;
  u16* hid = (u16*)ws;     ws += SZ_HID * 2;
  u16* pA  = hid;          // alias: patch A-matrix (M*768) fits in hid (M*1536), used before hid
  u16* wT  = (u16*)ws;
  float* pooled = (float*)ub;  // reuse ub at the end (free after last recur)
  float* hwT = (float*)hid;    // reuse hid at the end (free after last gemm3)

  // wT layout (elems): patchT[294912]; per d: WiT[147456] WgT[147456] w1T[589824] w2T[589824]
  const size_t PER_D = 1474560;
  u16* patchT = wT;
  u16* ugT0 = wT + 294912;
  u16* w1T0 = wT + 294912 + 294912;
  u16* w2T0 = wT + 294912 + 294912 + 589824;

  dim3 tb(32, 8);
  k_tcast<<<dim3(12, 24, 1), tb, 0, stream>>>(patch_w, patchT, 768, 384, (size_t)0, (size_t)0);
  k_tcast<<<dim3(12, 12, 12), tb, 0, stream>>>(w_in, ugT0, 384, 384, (size_t)147456, PER_D);
  k_tcast<<<dim3(12, 12, 12), tb, 0, stream>>>(w_g, ugT0 + 147456, 384, 384, (size_t)147456, PER_D);
  k_tcast<<<dim3(48, 12, 12), tb, 0, stream>>>(w1, w1T0, 384, 1536, (size_t)589824, PER_D);
  k_tcast<<<dim3(12, 48, 12), tb, 0, stream>>>(w2, w2T0, 1536, 384, (size_t)589824, PER_D);

  k_patch_extract<<<18816, 256, 0, stream>>>(x, pA);

  // patch embed GEMM: h = pA @ patch_w + patch_b + pos  (64x128 tiles: 3x98)
  k_gemm<0><<<dim3(3, 98), 256, 0, stream>>>(pA, patchT, 768, 384, patch_b, nullptr,
                                             h, nullptr, nullptr, pos);

  for (int d = 0; d < 12; ++d) {
    const u16* ugT = ugT0 + (size_t)d * PER_D;
    const u16* w1T = w1T0 + (size_t)d * PER_D;
    const u16* w2T = w2T0 + (size_t)d * PER_D;
    k_ln<<<1568, 256, 0, stream>>>(h, z, ln1_s + (size_t)d * 384, ln1_b + (size_t)d * 384);
    k_gemm<1><<<dim3(6, 98), 256, 0, stream>>>(z, ugT, 384, 768, b_in + (size_t)d * 384,
                                               b_g + (size_t)d * 384, nullptr, ub, gb, nullptr);
    k_recur<<<dim3(32, 48), 256, 0, stream>>>(h, ub, gb, k_dw + (size_t)d * 3456);
    k_ln<<<1568, 256, 0, stream>>>(h, z, ln2_s + (size_t)d * 384, ln2_b + (size_t)d * 384);
    k_gemm<2><<<dim3(12, 98), 256, 0, stream>>>(z, w1T, 384, 1536, b1 + (size_t)d * 1536,
                                                nullptr, nullptr, hid, nullptr, nullptr);
    k_gemm<3><<<dim3(3, 98), 256, 0, stream>>>(hid, w2T, 1536, 384, b2 + (size_t)d * 384,
                                               nullptr, h, nullptr, nullptr, h);
  }

  // transpose head_w (384,1000) -> hwT (1000,384) fp32 (hid buffer is free now)
  k_tcastf<<<dim3(32, 12), tb, 0, stream>>>(head_w, hwT, 384, 1000);

  k_ln<<<1568, 256, 0, stream>>>(h, z, lnf_s, lnf_b);
  k_pool<<<32, 384, 0, stream>>>(z, pooled);
  k_head<<<8000, 256, 0, stream>>>(pooled, hwT, head_b, out);
}